// Round 2
// baseline (885.327 us; speedup 1.0000x reference)
//
#include <hip/hip_runtime.h>
#include <hip/hip_bf16.h>

#define NROWS 100000
#define NB2   256    // split-K blocks for K^T V
#define RPB   391    // rows per K2 block (256*391 >= 100000)
#define LDP   264    // LDS row pitch (shorts): 256 + 8 pad

typedef short bf16x8 __attribute__((ext_vector_type(8)));
typedef float f32x4  __attribute__((ext_vector_type(4)));

__device__ __forceinline__ float bf2f(short s) {
    unsigned u = ((unsigned)(unsigned short)s) << 16;
    return __builtin_bit_cast(float, u);
}
__device__ __forceinline__ short f2bf(float f) {
    return __builtin_bit_cast(short, __float2bfloat16(f));
}

// ---------------- K0: convert Wq|Wk|Wv (fp32) -> concatenated bf16 --------
__global__ __launch_bounds__(256) void k_cvtw(
    const float* __restrict__ Wq, const float* __restrict__ Wk,
    const float* __restrict__ Wv, short* __restrict__ Wbf)
{
    const int i = blockIdx.x * 256 + threadIdx.x;   // 0..196607
    const float* src = (i < 65536) ? Wq : (i < 131072 ? Wk : Wv);
    Wbf[i] = f2bf(src[i & 65535]);
}

// ---------------- K1: fused QKV GEMM (MFMA 16x16x32 bf16) -----------------
// grid 1563: each block handles 64 rows, all 12 (seg,col) 64x64 tiles.
__global__ __launch_bounds__(256) void k_qkv(
    const float* __restrict__ xq, const float* __restrict__ xs,
    const short* __restrict__ Wbf,
    const float* __restrict__ bq, const float* __restrict__ bk,
    const float* __restrict__ bv,
    short* __restrict__ qo, short* __restrict__ ko, short* __restrict__ vo,
    float* __restrict__ sq_q)
{
    __shared__ short lq[64][LDP];
    __shared__ short ls[64][LDP];
    const int t = threadIdx.x;
    const int row0 = blockIdx.x * 64;

    // stage fp32 x -> bf16 LDS (both matrices), rows clamped
    for (int i = t; i < 4096; i += 256) {
        const int r = i >> 6, c4 = (i & 63) << 2;
        const size_t grow = (size_t)min(row0 + r, NROWS - 1);
        float4 a = *(const float4*)(xq + grow * 256 + c4);
        float4 b = *(const float4*)(xs + grow * 256 + c4);
        short4 pa, pb;
        pa.x = f2bf(a.x); pa.y = f2bf(a.y); pa.z = f2bf(a.z); pa.w = f2bf(a.w);
        pb.x = f2bf(b.x); pb.y = f2bf(b.y); pb.z = f2bf(b.z); pb.w = f2bf(b.w);
        *(short4*)&lq[r][c4] = pa;
        *(short4*)&ls[r][c4] = pb;
    }
    __syncthreads();

    const int wave = t >> 6, lane = t & 63;
    const int lrow = lane & 15, quad = lane >> 4;
    const int wrow = wave * 16;
    float ssq = 0.f;

    for (int tile = 0; tile < 12; ++tile) {
        const int seg = tile >> 2, col0 = (tile & 3) << 6;
        const short (*A)[LDP] = (seg == 0) ? lq : ls;
        const short* W  = Wbf + seg * 65536;
        const float* Bb = (seg == 0) ? bq : (seg == 1 ? bk : bv);
        short* O        = (seg == 0) ? qo : (seg == 1 ? ko : vo);

        f32x4 acc[4] = {};
#pragma unroll
        for (int k0 = 0; k0 < 256; k0 += 32) {
            bf16x8 a = *(const bf16x8*)&A[wrow + lrow][k0 + quad * 8];
#pragma unroll
            for (int c = 0; c < 4; ++c) {
                bf16x8 b = *(const bf16x8*)(W + (size_t)(col0 + c * 16 + lrow) * 256
                                              + k0 + quad * 8);
                acc[c] = __builtin_amdgcn_mfma_f32_16x16x32_bf16(a, b, acc[c], 0, 0, 0);
            }
        }
#pragma unroll
        for (int c = 0; c < 4; ++c) {
            const int col = col0 + c * 16 + lrow;
            const float bias = Bb[col];
#pragma unroll
            for (int r = 0; r < 4; ++r) {
                const int row = row0 + wrow + quad * 4 + r;
                if (row < NROWS) {
                    const float val = acc[c][r] + bias;
                    O[(size_t)row * 256 + col] = f2bf(val);
                    if (seg == 0) ssq += val * val;
                }
            }
        }
    }
    __shared__ float red[256];
    red[t] = ssq;
    __syncthreads();
    for (int s = 128; s > 0; s >>= 1) {
        if (t < s) red[t] += red[t + s];
        __syncthreads();
    }
    if (t == 0) atomicAdd(sq_q, red[0]);
}

// ---------------- K2: split-K kvsT[h][d][m] partials + ks_sum + sum(k^2) --
__global__ __launch_bounds__(256) void k_kv(
    const short* __restrict__ ko, const short* __restrict__ vo,
    float* __restrict__ part, float* __restrict__ ks_sum, float* __restrict__ sq_k)
{
    __shared__ float lk[8][256];
    __shared__ float lv[8][256];
    const int t  = threadIdx.x;
    const int h  = t >> 6;
    const int tm = (t >> 3) & 7, td = t & 7;
    const int m0 = tm * 8, d0 = td * 8;
    const int start = blockIdx.x * RPB;
    const int end   = min(start + RPB, NROWS);

    float acc[64];
#pragma unroll
    for (int i = 0; i < 64; ++i) acc[i] = 0.f;
    float ksp = 0.f, sqp = 0.f;

    for (int l0 = start; l0 < end; l0 += 8) {
        __syncthreads();
#pragma unroll
        for (int j = 0; j < 8; ++j) {
            const int row = l0 + j;
            float kv = 0.f, vv = 0.f;
            if (row < end) {
                kv = bf2f(ko[(size_t)row * 256 + t]);
                vv = bf2f(vo[(size_t)row * 256 + t]);
            }
            lk[j][t] = kv; lv[j][t] = vv;
            ksp += kv; sqp += kv * kv;
        }
        __syncthreads();
#pragma unroll
        for (int j = 0; j < 8; ++j) {
            float4 ka = *(const float4*)&lk[j][h * 64 + m0];
            float4 kb = *(const float4*)&lk[j][h * 64 + m0 + 4];
            float4 va = *(const float4*)&lv[j][h * 64 + d0];
            float4 vb = *(const float4*)&lv[j][h * 64 + d0 + 4];
            const float kr[8] = {ka.x, ka.y, ka.z, ka.w, kb.x, kb.y, kb.z, kb.w};
            const float vr[8] = {va.x, va.y, va.z, va.w, vb.x, vb.y, vb.z, vb.w};
#pragma unroll
            for (int jd = 0; jd < 8; ++jd)
#pragma unroll
                for (int im = 0; im < 8; ++im)
                    acc[jd * 8 + im] += vr[jd] * kr[im];
        }
    }
    float* pb = part + (size_t)blockIdx.x * 16384 + h * 4096 + d0 * 64 + m0;
#pragma unroll
    for (int jd = 0; jd < 8; ++jd) {
        *(float4*)(pb + jd * 64)     = make_float4(acc[jd*8+0], acc[jd*8+1], acc[jd*8+2], acc[jd*8+3]);
        *(float4*)(pb + jd * 64 + 4) = make_float4(acc[jd*8+4], acc[jd*8+5], acc[jd*8+6], acc[jd*8+7]);
    }
    atomicAdd(&ks_sum[t], ksp);
    __syncthreads();
    lk[0][t] = sqp;
    __syncthreads();
    for (int s = 128; s > 0; s >>= 1) {
        if (t < s) lk[0][t] += lk[0][t + s];
        __syncthreads();
    }
    if (t == 0) atomicAdd(sq_k, lk[0][0]);
}

// ---------------- K2b: reduce partials -> scaled bf16 kvsT ----------------
__global__ __launch_bounds__(256) void k_red(
    const float* __restrict__ part, const float* __restrict__ sq_q,
    const float* __restrict__ sq_k, short* __restrict__ kvsTbf)
{
    const int i = blockIdx.x * 256 + threadIdx.x;   // 0..16383
    float s = 0.f;
    for (int b = 0; b < NB2; ++b) s += part[(size_t)b * 16384 + i];
    const float scale = __frsqrt_rn(sq_q[0]) * __frsqrt_rn(sq_k[0]);
    kvsTbf[i] = f2bf(s * scale);
}

// ---------------- K3a: normalizer 1/(q . ks_sum * scale + N) --------------
__global__ __launch_bounds__(256) void k_nrm(
    const short* __restrict__ qo, const float* __restrict__ ks_sum,
    const float* __restrict__ sq_q, const float* __restrict__ sq_k,
    float* __restrict__ nrm_inv)
{
    __shared__ float kss[256];
    kss[threadIdx.x] = ks_sum[threadIdx.x];
    __syncthreads();
    const int gid = blockIdx.x * 256 + threadIdx.x;
    if (gid >= NROWS * 4) return;
    const int n = gid >> 2, h = gid & 3;
    const short* qr = qo + (size_t)n * 256 + h * 64;
    float dot = 0.f;
#pragma unroll
    for (int m0 = 0; m0 < 64; m0 += 8) {
        bf16x8 v = *(const bf16x8*)(qr + m0);
#pragma unroll
        for (int j = 0; j < 8; ++j) dot += bf2f(v[j]) * kss[h * 64 + m0 + j];
    }
    const float scale = __frsqrt_rn(sq_q[0]) * __frsqrt_rn(sq_k[0]);
    nrm_inv[gid] = 1.f / (dot * scale + (float)NROWS);
}

// ---------------- K3: out = mean_h (q.kvs~ + N v) * nrm_inv ---------------
__global__ __launch_bounds__(256) void k_out(
    const short* __restrict__ qo, const short* __restrict__ vo,
    const short* __restrict__ kvsTbf, const float* __restrict__ nrm_inv,
    float* __restrict__ out)
{
    const int wave = threadIdx.x >> 6, lane = threadIdx.x & 63;
    const int lrow = lane & 15, quad = lane >> 4;
    const int row0 = blockIdx.x * 64 + wave * 16;
    const int arow = min(row0 + lrow, NROWS - 1);

    float osum[4][4] = {};
#pragma unroll
    for (int h = 0; h < 4; ++h) {
        f32x4 acc[4] = {};
#pragma unroll
        for (int k0 = 0; k0 < 64; k0 += 32) {
            bf16x8 a = *(const bf16x8*)(qo + (size_t)arow * 256 + h * 64 + k0 + quad * 8);
#pragma unroll
            for (int c = 0; c < 4; ++c) {
                bf16x8 b = *(const bf16x8*)(kvsTbf + (h * 64 + c * 16 + lrow) * 64
                                              + k0 + quad * 8);
                acc[c] = __builtin_amdgcn_mfma_f32_16x16x32_bf16(a, b, acc[c], 0, 0, 0);
            }
        }
#pragma unroll
        for (int r = 0; r < 4; ++r) {
            const int row = row0 + quad * 4 + r;
            if (row < NROWS) {
                const float ni = nrm_inv[row * 4 + h];
#pragma unroll
                for (int c = 0; c < 4; ++c) {
                    const int d = c * 16 + lrow;
                    const float num = acc[c][r]
                        + 100000.f * bf2f(vo[(size_t)row * 256 + h * 64 + d]);
                    osum[c][r] += num * ni;
                }
            }
        }
    }
#pragma unroll
    for (int r = 0; r < 4; ++r) {
        const int row = row0 + quad * 4 + r;
        if (row < NROWS) {
#pragma unroll
            for (int c = 0; c < 4; ++c)
                out[(size_t)row * 64 + c * 16 + lrow] = 0.25f * osum[c][r];
        }
    }
}

extern "C" void kernel_launch(void* const* d_in, const int* in_sizes, int n_in,
                              void* d_out, int out_size, void* d_ws, size_t ws_size,
                              hipStream_t stream)
{
    const float* xq = (const float*)d_in[0];
    const float* xs = (const float*)d_in[1];
    const float* Wq = (const float*)d_in[2];
    const float* bq = (const float*)d_in[3];
    const float* Wk = (const float*)d_in[4];
    const float* bk = (const float*)d_in[5];
    const float* Wv = (const float*)d_in[6];
    const float* bv = (const float*)d_in[7];

    char* ws = (char*)d_ws;
    short* Wbf    = (short*)(ws + 0);            // 393,216 B
    short* qo     = (short*)(ws + 393216);       // 51.2 MB
    short* ko     = (short*)(ws + 51593216);
    short* vo     = (short*)(ws + 102793216);
    float* sq_q   = (float*)(ws + 153993216);
    float* sq_k   = (float*)(ws + 153993220);
    float* ks_sum = (float*)(ws + 153993472);    // 256 floats
    short* kvsTbf = (short*)(ws + 153994496);    // 32,768 B
    float* nrm_inv= (float*)(ws + 154027264);    // 1.6 MB
    float* part   = (float*)(ws + 155627264);    // 256*16384*4 = 16.7 MB -> end 172,404,480

    hipMemsetAsync(ws + 153993216, 0, 1280, stream);   // sq_q, sq_k, ks_sum

    k_cvtw<<<dim3(768),  256, 0, stream>>>(Wq, Wk, Wv, Wbf);
    k_qkv <<<dim3(1563), 256, 0, stream>>>(xq, xs, Wbf, bq, bk, bv, qo, ko, vo, sq_q);
    k_kv  <<<dim3(NB2),  256, 0, stream>>>(ko, vo, part, ks_sum, sq_k);
    k_red <<<dim3(64),   256, 0, stream>>>(part, sq_q, sq_k, kvsTbf);
    k_nrm <<<dim3(1563), 256, 0, stream>>>(qo, ks_sum, sq_q, sq_k, nrm_inv);
    k_out <<<dim3(1563), 256, 0, stream>>>(qo, vo, kvsTbf, nrm_inv, (float*)d_out);
}

// Round 3
// 219.800 us; speedup vs baseline: 4.0279x; 4.0279x over previous
//
#include <hip/hip_runtime.h>
#include <hip/hip_bf16.h>

#define NROWS 100000
#define LDP   264   // LDS W-tile pitch in shorts: 256 + 8 pad (conflict-free b128 reads)

typedef short bf16x8 __attribute__((ext_vector_type(8)));
typedef float f32x4  __attribute__((ext_vector_type(4)));

__device__ __forceinline__ short f2bf(float f) {
    return __builtin_bit_cast(short, __float2bfloat16(f));
}

// ---- K0: Wmean[64][256] = 0.25 * sum_h Wv[h*64+d][k]  (fp32 -> bf16), bmean ----
__global__ __launch_bounds__(256) void k_prep(
    const float* __restrict__ Wv, const float* __restrict__ bv,
    short* __restrict__ Wmb, float* __restrict__ bmb)
{
    const int i = blockIdx.x * 256 + threadIdx.x;   // 0..16383
    const int d = i >> 8, k = i & 255;
    float s = 0.f;
#pragma unroll
    for (int h = 0; h < 4; ++h) s += Wv[(size_t)(h * 64 + d) * 256 + k];
    Wmb[i] = f2bf(0.25f * s);
    if (i < 64) {
        float b = 0.f;
#pragma unroll
        for (int h = 0; h < 4; ++h) b += bv[h * 64 + i];
        bmb[i] = 0.25f * b;
    }
}

// ---- K1: out[n][d] = xs[n] . Wmean[d] + bmean[d]  (MFMA 16x16x32 bf16) ----
// 64 rows/block, 16 rows/wave (m89 fragment pattern). W in LDS (staged once,
// single barrier); x streamed direct from global fp32, converted in regs.
__global__ __launch_bounds__(256, 4) void k_gemm(
    const float* __restrict__ xs, const short* __restrict__ Wmb,
    const float* __restrict__ bmb, float* __restrict__ out)
{
    __shared__ short lw[64][LDP];
    __shared__ float lb[64];
    const int t = threadIdx.x;

    // stage W: 2048 16-B chunks, 8 per thread, coalesced; padded LDS rows
    for (int c = t; c < 2048; c += 256) {
        const int row = c >> 5, pos = (c & 31) << 3;   // pos in shorts
        *(bf16x8*)&lw[row][pos] = *(const bf16x8*)(Wmb + row * 256 + pos);
    }
    if (t < 64) lb[t] = bmb[t];
    __syncthreads();

    const int wave = t >> 6, lane = t & 63;
    const int lrow = lane & 15, quad = lane >> 4;
    const int row0 = blockIdx.x * 64 + wave * 16;
    const int arow = min(row0 + lrow, NROWS - 1);
    const float* xp = xs + (size_t)arow * 256 + quad * 8;

    f32x4 acc[4] = {};
#pragma unroll
    for (int k0 = 0; k0 < 256; k0 += 32) {
        const f32x4 xa = *(const f32x4*)(xp + k0);
        const f32x4 xb = *(const f32x4*)(xp + k0 + 4);
        bf16x8 a;
        a[0] = f2bf(xa[0]); a[1] = f2bf(xa[1]); a[2] = f2bf(xa[2]); a[3] = f2bf(xa[3]);
        a[4] = f2bf(xb[0]); a[5] = f2bf(xb[1]); a[6] = f2bf(xb[2]); a[7] = f2bf(xb[3]);
#pragma unroll
        for (int c = 0; c < 4; ++c) {
            const bf16x8 b = *(const bf16x8*)&lw[c * 16 + lrow][k0 + quad * 8];
            acc[c] = __builtin_amdgcn_mfma_f32_16x16x32_bf16(a, b, acc[c], 0, 0, 0);
        }
    }

    // epilogue: bias + fp32 store. For fixed (c,r): 16 lanes write 64 B
    // contiguous per quad-row -> every store covers full 64-B segments.
#pragma unroll
    for (int c = 0; c < 4; ++c) {
        const float bias = lb[c * 16 + lrow];
#pragma unroll
        for (int r = 0; r < 4; ++r) {
            const int row = row0 + quad * 4 + r;
            if (row < NROWS)
                out[(size_t)row * 64 + c * 16 + lrow] = acc[c][r] + bias;
        }
    }
}

extern "C" void kernel_launch(void* const* d_in, const int* in_sizes, int n_in,
                              void* d_out, int out_size, void* d_ws, size_t ws_size,
                              hipStream_t stream)
{
    const float* xs = (const float*)d_in[1];   // source_input
    const float* Wv = (const float*)d_in[6];   // Wv_w [256][256]
    const float* bv = (const float*)d_in[7];   // Wv_b [256]

    char* ws = (char*)d_ws;
    short* Wmb = (short*)(ws + 0);       // 32 KB bf16 Wmean
    float* bmb = (float*)(ws + 32768);   // 256 B bmean

    k_prep<<<dim3(64),   256, 0, stream>>>(Wv, bv, Wmb, bmb);
    k_gemm<<<dim3(1563), 256, 0, stream>>>(xs, Wmb, bmb, (float*)d_out);
}